// Round 9
// baseline (740.851 us; speedup 1.0000x reference)
//
#include <hip/hip_runtime.h>
#include <hip/hip_bf16.h>
#include <math.h>

using bf16 = __hip_bfloat16;
typedef __attribute__((ext_vector_type(8))) short s8v;   // 8 x bf16 raw (4 VGPRs)
typedef __attribute__((ext_vector_type(4))) float f32x4;

#define B_  4
#define S_  2048
#define D_  1024
#define E_  1536
#define M_  (B_*S_)     // 8192 tokens
#define BE_ (B_*E_)     // 6144 sequences
#define NCH 128         // scan chunks (vec8 scan: 3072 blocks, 16 steps/chunk)
#define CHS (S_/NCH)    // 16 steps per chunk
#define TS_ 16          // dwconv tokens per block
#define DWB (M_/TS_)    // 512 dwconv blocks

__device__ __forceinline__ float b2f(bf16 h) { return __bfloat162float(h); }
__device__ __forceinline__ bf16  f2b(float f) { return __float2bfloat16(f); }
__device__ __forceinline__ float su2f(short v) {        // raw bf16 bits -> f32 (exact)
  unsigned u = ((unsigned)(unsigned short)v) << 16;
  return __builtin_bit_cast(float, u);
}

struct __align__(8)  bh4 { bf16 h[4]; };
struct __align__(16) bh8 { bf16 h[8]; };

__device__ __forceinline__ void gld16(const void* g, void* l) {
  __builtin_amdgcn_global_load_lds((const __attribute__((address_space(1))) void*)g,
                                   (__attribute__((address_space(3))) void*)l, 16, 0, 0);
}

// ---------------- fused prep: dwconv (blocks 0..511) + fp32->bf16 cvt of all 7 weights ----------------
__global__ __launch_bounds__(256) void prep_k(const float* __restrict__ x,
                                              const float* __restrict__ cw,
                                              const float* __restrict__ cb,
                                              bf16* __restrict__ dw_out,
                                              const float* __restrict__ s0,
                                              const float* __restrict__ s1,
                                              const float* __restrict__ s2,
                                              const float* __restrict__ s3,
                                              const float* __restrict__ s4,
                                              const float* __restrict__ s5,
                                              const float* __restrict__ s6,
                                              bf16* __restrict__ wdst)
{
  if (blockIdx.x < DWB) {
    int m0 = blockIdx.x * TS_;
    int sr0 = m0 & (S_ - 1);
    int d = threadIdx.x * 4;
    float wf[4][4];
#pragma unroll
    for (int i = 0; i < 4; ++i) {
      float4 wr = *(const float4*)(cw + (d + i) * 4);
      wf[i][0] = wr.x; wf[i][1] = wr.y; wf[i][2] = wr.z; wf[i][3] = wr.w;
    }
    float4 bb = *(const float4*)(cb + d);
    float4 xr[TS_ + 3];
#pragma unroll
    for (int j = 0; j < TS_ + 3; ++j) {
      int srow = sr0 - 3 + j;
      if (srow >= 0) xr[j] = *(const float4*)(x + (size_t)(m0 - 3 + j) * D_ + d);
      else           xr[j] = make_float4(0.f, 0.f, 0.f, 0.f);
    }
#pragma unroll
    for (int t = 0; t < TS_; ++t) {
      float a0 = bb.x, a1 = bb.y, a2 = bb.z, a3 = bb.w;
#pragma unroll
      for (int k = 0; k < 4; ++k) {
        float4 xv = xr[t + k];
        a0 += xv.x * wf[0][k];
        a1 += xv.y * wf[1][k];
        a2 += xv.z * wf[2][k];
        a3 += xv.w * wf[3][k];
      }
      bh4 ov;
      ov.h[0] = f2b(a0); ov.h[1] = f2b(a1); ov.h[2] = f2b(a2); ov.h[3] = f2b(a3);
      *(bh4*)(dw_out + (size_t)(m0 + t) * D_ + d) = ov;
    }
  } else {
    size_t i = ((size_t)(blockIdx.x - DWB) * 256 + threadIdx.x) * 4;
    const float* s; size_t off;
    if (i < 4194304) {
      if (i < 1048576)      { s = s0; off = 0; }
      else if (i < 2621440) { s = s1; off = 1048576; }
      else                  { s = s2; off = 2621440; }
    } else if (i < 7340032) {
      if (i < 5767168)      { s = s3; off = 4194304; }
      else                  { s = s4; off = 5767168; }
    } else {
      if (i < 11534336)     { s = s5; off = 7340032; }
      else                  { s = s6; off = 11534336; }
    }
    float4 v = *(const float4*)(s + (i - off));
    bh4 o;
    o.h[0] = f2b(v.x); o.h[1] = f2b(v.y); o.h[2] = f2b(v.z); o.h[3] = f2b(v.w);
    *(bh4*)(wdst + i) = o;
  }
}

// ---------------- shared epilogue (R5 set) ----------------
template<int EPI>
__device__ __forceinline__ void epi_store(float v, int row, int col, int N,
                                          const float* __restrict__ bias,
                                          const float* __restrict__ resid,
                                          bf16* outH, bf16* outH2, float* outF)
{
  size_t idx = (size_t)row * N + col;
  if constexpr (EPI == 0) {
    outH[idx] = f2b(v + bias[col] + resid[idx]);
  } else if constexpr (EPI == 1) {
    if (col < 1536) outH [(size_t)row * 1536 + col]        = f2b(v);
    else            outH2[(size_t)row * 1536 + col - 1536] = f2b(v);
  } else if constexpr (EPI == 2) {
    float gh = (v >= 0.f) ? (v + 0.5f) : (1.f / (1.f + expf(-v)));
    float iv = 1.f / (1.f + expf(-b2f(outH[idx])));
    outH[idx] = f2b(gh * iv);
  } else if constexpr (EPI == 3) {
    outH[idx] = f2b(v + resid[idx]);
  } else if constexpr (EPI == 4) {
    float u = v + bias[col];
    outH[idx] = f2b(0.5f * u * (1.f + erff(u * 0.70710678118f)));
  } else {
    outF[idx] = v + bias[col];
  }
}

// ======== GEMM 128x128 (proven R5): C(M,N)=A(M,K,lda)*B^T(N,K,ldb), bf16, swizzled LDS ========
// Sync structure frozen (stage-all -> sync -> 32 MFMA 16x16x32 -> sync). Pointer-bump
// staging; no XCD swizzle (R5/R7/R8 A/B: time-neutral, lower FETCH without); 16x16
// fragments (R6: 32x32 read pattern -> 8.4M bank conflicts). Row r chunk slot s holds
// col-group s^(r&7): measured 0-conflict.
template<int EPI>
__global__ __launch_bounds__(256) void gemm_ab(const bf16* __restrict__ A, int lda,
                                               const bf16* __restrict__ Bb, int ldb,
                                               const float* __restrict__ bias,
                                               const float* __restrict__ resid,
                                               bf16* outH, bf16* outH2, float* outF,
                                               int M, int N, int K)
{
  __shared__ __align__(16) bf16 lsA[128 * 64];
  __shared__ __align__(16) bf16 lsB[128 * 64];
  const int tid  = threadIdx.x;
  const int lane = tid & 63;
  const int wave = tid >> 6;
  const int m0 = blockIdx.y * 128, n0 = blockIdx.x * 128;
  const int wm = (wave >> 1) * 64, wn = (wave & 1) * 64;
  const int r = lane & 15, q = lane >> 4;
  const int sw = r & 7;
  f32x4 acc[4][4] = {};

  const bf16* pa[4]; const bf16* pb[4]; int dst[4];
#pragma unroll
  for (int i = 0; i < 4; ++i) {
    int c = i * 256 + tid;                     // LDS chunk id 0..1023
    int row = c >> 3, cc = (c & 7) ^ (row & 7);
    pa[i] = A  + (size_t)(m0 + row) * lda + cc * 8;
    pb[i] = Bb + (size_t)(n0 + row) * ldb + cc * 8;
    dst[i] = c * 16;
  }

  for (int k0 = 0; k0 < K; k0 += 64) {
#pragma unroll
    for (int i = 0; i < 4; ++i) {
      gld16(pa[i], (char*)lsA + dst[i]);
      gld16(pb[i], (char*)lsB + dst[i]);
      pa[i] += 64; pb[i] += 64;
    }
    __syncthreads();
#pragma unroll
    for (int kk = 0; kk < 64; kk += 32) {
      const int j = (kk >> 3) + q;
      s8v af[4], bfr[4];
#pragma unroll
      for (int t = 0; t < 4; ++t) {
        af[t]  = *(const s8v*)((char*)lsA + (((wm + t * 16 + r) << 3) + (j ^ sw)) * 16);
        bfr[t] = *(const s8v*)((char*)lsB + (((wn + t * 16 + r) << 3) + (j ^ sw)) * 16);
      }
#pragma unroll
      for (int mi = 0; mi < 4; ++mi)
#pragma unroll
        for (int ni = 0; ni < 4; ++ni)
          acc[mi][ni] = __builtin_amdgcn_mfma_f32_16x16x32_bf16(af[mi], bfr[ni], acc[mi][ni], 0, 0, 0);
    }
    __syncthreads();
  }

#pragma unroll
  for (int mi = 0; mi < 4; ++mi)
#pragma unroll
    for (int j = 0; j < 4; ++j) {
      int row = m0 + wm + mi * 16 + q * 4 + j;
#pragma unroll
      for (int ni = 0; ni < 4; ++ni)
        epi_store<EPI>(acc[mi][ni][j], row, n0 + wn + ni * 16 + r, N, bias, resid, outH, outH2, outF);
    }
}

// ---------------- LayerNorm, wave-per-row: 4 rows/block, shuffle-only reduction ----------------
// No LDS, no barriers; each wave loads its row as 2x16B/lane (2048B coalesced).
__global__ __launch_bounds__(256) void ln_k(const bf16* __restrict__ y,
                                            const float* __restrict__ g,
                                            const float* __restrict__ b,
                                            bf16* __restrict__ out)
{
  int wv = threadIdx.x >> 6, lane = threadIdx.x & 63;
  int row = blockIdx.x * 4 + wv;
  const bf16* yr = y + (size_t)row * D_;
  bh8 a = ((const bh8*)yr)[lane];
  bh8 c = ((const bh8*)yr)[64 + lane];
  float va[16];
#pragma unroll
  for (int j = 0; j < 8; ++j) { va[j] = b2f(a.h[j]); va[8 + j] = b2f(c.h[j]); }
  float s = 0.f;
#pragma unroll
  for (int j = 0; j < 16; ++j) s += va[j];
#pragma unroll
  for (int o = 32; o; o >>= 1) s += __shfl_down(s, o);
  float mu = __shfl(s, 0) * (1.f / D_);
  float qq = 0.f;
#pragma unroll
  for (int j = 0; j < 16; ++j) { va[j] -= mu; qq += va[j] * va[j]; }
#pragma unroll
  for (int o = 32; o; o >>= 1) qq += __shfl_down(qq, o);
  float inv = rsqrtf(__shfl(qq, 0) * (1.f / D_) + 1e-5f);

  int c0 = lane * 8, c1 = 512 + lane * 8;
  float4 g0 = *(const float4*)(g + c0),  g1 = *(const float4*)(g + c0 + 4);
  float4 g2 = *(const float4*)(g + c1),  g3 = *(const float4*)(g + c1 + 4);
  float4 b0 = *(const float4*)(b + c0),  b1 = *(const float4*)(b + c0 + 4);
  float4 b2 = *(const float4*)(b + c1),  b3 = *(const float4*)(b + c1 + 4);
  float gg[16] = {g0.x,g0.y,g0.z,g0.w, g1.x,g1.y,g1.z,g1.w,
                  g2.x,g2.y,g2.z,g2.w, g3.x,g3.y,g3.z,g3.w};
  float bb[16] = {b0.x,b0.y,b0.z,b0.w, b1.x,b1.y,b1.z,b1.w,
                  b2.x,b2.y,b2.z,b2.w, b3.x,b3.y,b3.z,b3.w};
  bh8 o1, o2;
#pragma unroll
  for (int j = 0; j < 8; ++j) {
    o1.h[j] = f2b(va[j]     * inv * gg[j]     + bb[j]);
    o2.h[j] = f2b(va[8 + j] * inv * gg[8 + j] + bb[8 + j]);
  }
  bf16* orow = out + (size_t)row * D_;
  ((bh8*)orow)[lane]      = o1;
  ((bh8*)orow)[64 + lane] = o2;
}

// ---------------- chunked linear-recurrence scan, vec8 (R5): h' = sigmoid(fpre)*h + g ----------------
__global__ __launch_bounds__(256) void scanA2_k(const bf16* __restrict__ fpre,
                                                const bf16* __restrict__ g,
                                                float* __restrict__ Fc, float* __restrict__ Gc)
{
  int t = blockIdx.x * 256 + threadIdx.x;       // 0 .. NCH*BE_/8-1
  int c = t / (BE_ / 8);
  int col = t % (BE_ / 8);
  int be8 = col * 8;
  int b = be8 / E_, e = be8 % E_;
  size_t idx = (size_t)b * S_ * E_ + (size_t)c * CHS * E_ + e;
  float F[8], G[8];
#pragma unroll
  for (int j = 0; j < 8; ++j) { F[j] = 1.f; G[j] = 0.f; }
  for (int sl = 0; sl < CHS; ++sl, idx += E_) {
    s8v fv8 = *(const s8v*)(fpre + idx);
    s8v gv8 = *(const s8v*)(g + idx);
#pragma unroll
    for (int j = 0; j < 8; ++j) {
      float fv = 1.f / (1.f + expf(-su2f(fv8[j])));
      F[j] *= fv;
      G[j] = fv * G[j] + su2f(gv8[j]);
    }
  }
  size_t o = (size_t)c * BE_ + be8;
  *(float4*)(Fc + o)     = make_float4(F[0], F[1], F[2], F[3]);
  *(float4*)(Fc + o + 4) = make_float4(F[4], F[5], F[6], F[7]);
  *(float4*)(Gc + o)     = make_float4(G[0], G[1], G[2], G[3]);
  *(float4*)(Gc + o + 4) = make_float4(G[4], G[5], G[6], G[7]);
}

__global__ __launch_bounds__(256) void scanB_k(const float* __restrict__ Fc,
                                               const float* __restrict__ Gc,
                                               float* __restrict__ hst)
{
  int be = blockIdx.x * 256 + threadIdx.x;
  float h = 0.5f;
#pragma unroll 16
  for (int c = 0; c < NCH; ++c) {
    hst[c * BE_ + be] = h;
    h = Fc[c * BE_ + be] * h + Gc[c * BE_ + be];
  }
}

__global__ __launch_bounds__(256) void scanC2_k(const bf16* __restrict__ fpre,
                                                bf16* g,
                                                const float* __restrict__ hst)
{
  int t = blockIdx.x * 256 + threadIdx.x;
  int c = t / (BE_ / 8);
  int col = t % (BE_ / 8);
  int be8 = col * 8;
  int b = be8 / E_, e = be8 % E_;
  size_t idx = (size_t)b * S_ * E_ + (size_t)c * CHS * E_ + e;
  size_t o = (size_t)c * BE_ + be8;
  float4 h0 = *(const float4*)(hst + o);
  float4 h1 = *(const float4*)(hst + o + 4);
  float h[8] = {h0.x, h0.y, h0.z, h0.w, h1.x, h1.y, h1.z, h1.w};
  for (int sl = 0; sl < CHS; ++sl, idx += E_) {
    s8v fv8 = *(const s8v*)(fpre + idx);
    s8v gv8 = *(const s8v*)(g + idx);
    bh8 ov;
#pragma unroll
    for (int j = 0; j < 8; ++j) {
      float fv = 1.f / (1.f + expf(-su2f(fv8[j])));
      h[j] = fv * h[j] + su2f(gv8[j]);
      ov.h[j] = f2b(h[j]);
    }
    *(bh8*)(g + idx) = ov;
  }
}

extern "C" void kernel_launch(void* const* d_in, const int* in_sizes, int n_in,
                              void* d_out, int out_size, void* d_ws, size_t ws_size,
                              hipStream_t stream)
{
  (void)in_sizes; (void)n_in; (void)out_size; (void)ws_size;
  const float* x      = (const float*)d_in[0];
  const float* cdw_w  = (const float*)d_in[1];
  const float* cdw_b  = (const float*)d_in[2];
  const float* cpw_w  = (const float*)d_in[3];
  const float* cpw_b  = (const float*)d_in[4];
  const float* ln1_g  = (const float*)d_in[5];
  const float* ln1_b  = (const float*)d_in[6];
  const float* w_f    = (const float*)d_in[7];
  const float* w_i    = (const float*)d_in[8];
  const float* w_h    = (const float*)d_in[9];
  const float* w_down = (const float*)d_in[10];
  const float* ln2_g  = (const float*)d_in[11];
  const float* ln2_b  = (const float*)d_in[12];
  const float* mlp_w1 = (const float*)d_in[13];
  const float* mlp_b1 = (const float*)d_in[14];
  const float* mlp_w2 = (const float*)d_in[15];
  const float* mlp_b2 = (const float*)d_in[16];
  char* ws = (char*)d_ws;
  float* outF = (float*)d_out;

  // [0,16M)   dw_buf(conv) / xln(ln outputs); Fc/Gc/hst @[0,9.4M) during scans (xln dead)
  // [16,32M)  yb ; [16,80M) hmid (over yb/fpre/gvals, dead by then)
  // [32,58M)  fpre raw bf16 ; [58,80M) ipre raw -> g (RMW by g2) -> h in-place (scanC2)
  // [80,110M) bf16 weights: pw | wfi | wh | wd | w1 | w2
  bf16* dw_buf = (bf16*)(ws + 0);
  bf16* xln    = (bf16*)(ws + 0);
  float* Fc    = (float*)(ws + 0);          // 128*6144*4 = 3,145,728
  float* Gc    = (float*)(ws + 3145728);
  float* hst   = (float*)(ws + 6291456);    // ends 9,437,184 < 16M
  bf16* yb     = (bf16*)(ws + 16777216);
  bf16* hmid   = (bf16*)(ws + 16777216);
  bf16* fpre   = (bf16*)(ws + 33554432);
  bf16* gvals  = (bf16*)(ws + 58720256);
  bf16* pwb    = (bf16*)(ws + 83886080);
  bf16* wfib   = (bf16*)(ws + 85983232);
  bf16* whb    = (bf16*)(ws + 92274688);
  bf16* wdb    = (bf16*)(ws + 95420416);
  bf16* w1b    = (bf16*)(ws + 98566144);
  bf16* w2b    = (bf16*)(ws + 106954752);

  // fused: dwconv (512 blocks) + weight cvt (15360 blocks)
  prep_k<<<DWB + 15360, 256, 0, stream>>>(x, cdw_w, cdw_b, dw_buf,
                                          cpw_w, w_f, w_i, w_h, w_down, mlp_w1, mlp_w2, pwb);

  gemm_ab<0><<<dim3(8, 64), 256, 0, stream>>>(dw_buf, D_, pwb, D_, cpw_b, x, yb, nullptr, nullptr, M_, D_, D_);
  ln_k<<<M_/4, 256, 0, stream>>>(yb, ln1_g, ln1_b, xln);
  // fused f+i raw pre-activations (N=3072), then h RMW: g = gh(v)*sigmoid(ipre)
  gemm_ab<1><<<dim3(24, 64), 256, 0, stream>>>(xln, D_, wfib, D_, nullptr, nullptr, fpre, gvals, nullptr, M_, 3072, D_);
  gemm_ab<2><<<dim3(12, 64), 256, 0, stream>>>(xln, D_, whb, D_, nullptr, nullptr, gvals, nullptr, nullptr, M_, E_, D_);
  scanA2_k<<<(NCH*BE_/8)/256, 256, 0, stream>>>(fpre, gvals, Fc, Gc);
  scanB_k<<<BE_/256, 256, 0, stream>>>(Fc, Gc, hst);
  scanC2_k<<<(NCH*BE_/8)/256, 256, 0, stream>>>(fpre, gvals, hst);
  gemm_ab<3><<<dim3(8, 64), 256, 0, stream>>>(gvals, E_, wdb, E_, nullptr, x, yb, nullptr, nullptr, M_, D_, E_);
  ln_k<<<M_/4, 256, 0, stream>>>(yb, ln2_g, ln2_b, xln);
  // fused MLP: one N=4096 GEMM -> hmid, one K=4096 GEMM -> d_out (fp32, single write)
  gemm_ab<4><<<dim3(32, 64), 256, 0, stream>>>(xln, D_, w1b, D_, mlp_b1, nullptr, hmid, nullptr, nullptr, M_, 4*D_, D_);
  gemm_ab<5><<<dim3(8, 64), 256, 0, stream>>>(hmid, 4*D_, w2b, 4*D_, mlp_b2, nullptr, nullptr, nullptr, outF, M_, D_, 4*D_);
}

// Round 10
// 594.170 us; speedup vs baseline: 1.2469x; 1.2469x over previous
//
#include <hip/hip_runtime.h>
#include <hip/hip_bf16.h>
#include <math.h>

using bf16 = __hip_bfloat16;
typedef __attribute__((ext_vector_type(8))) short s8v;   // 8 x bf16 raw (4 VGPRs)
typedef __attribute__((ext_vector_type(4))) float f32x4;

#define B_  4
#define S_  2048
#define D_  1024
#define E_  1536
#define M_  (B_*S_)     // 8192 tokens
#define BE_ (B_*E_)     // 6144 sequences
#define NCH 128         // scan chunks (vec8 scan: 3072 blocks, 16 steps/chunk)
#define CHS (S_/NCH)    // 16 steps per chunk
#define TS_ 16          // dwconv tokens per block
#define DWB (M_/TS_)    // 512 dwconv blocks

__device__ __forceinline__ float b2f(bf16 h) { return __bfloat162float(h); }
__device__ __forceinline__ bf16  f2b(float f) { return __float2bfloat16(f); }
__device__ __forceinline__ float su2f(short v) {        // raw bf16 bits -> f32 (exact)
  unsigned u = ((unsigned)(unsigned short)v) << 16;
  return __builtin_bit_cast(float, u);
}

struct __align__(8)  bh4 { bf16 h[4]; };
struct __align__(16) bh8 { bf16 h[8]; };

__device__ __forceinline__ void gld16(const void* g, void* l) {
  __builtin_amdgcn_global_load_lds((const __attribute__((address_space(1))) void*)g,
                                   (__attribute__((address_space(3))) void*)l, 16, 0, 0);
}

// ---------------- fused prep: dwconv (blocks 0..511) + fp32->bf16 cvt of all 7 weights ----------------
__global__ __launch_bounds__(256) void prep_k(const float* __restrict__ x,
                                              const float* __restrict__ cw,
                                              const float* __restrict__ cb,
                                              bf16* __restrict__ dw_out,
                                              const float* __restrict__ s0,
                                              const float* __restrict__ s1,
                                              const float* __restrict__ s2,
                                              const float* __restrict__ s3,
                                              const float* __restrict__ s4,
                                              const float* __restrict__ s5,
                                              const float* __restrict__ s6,
                                              bf16* __restrict__ wdst)
{
  if (blockIdx.x < DWB) {
    int m0 = blockIdx.x * TS_;
    int sr0 = m0 & (S_ - 1);
    int d = threadIdx.x * 4;
    float wf[4][4];
#pragma unroll
    for (int i = 0; i < 4; ++i) {
      float4 wr = *(const float4*)(cw + (d + i) * 4);
      wf[i][0] = wr.x; wf[i][1] = wr.y; wf[i][2] = wr.z; wf[i][3] = wr.w;
    }
    float4 bb = *(const float4*)(cb + d);
    float4 xr[TS_ + 3];
#pragma unroll
    for (int j = 0; j < TS_ + 3; ++j) {
      int srow = sr0 - 3 + j;
      if (srow >= 0) xr[j] = *(const float4*)(x + (size_t)(m0 - 3 + j) * D_ + d);
      else           xr[j] = make_float4(0.f, 0.f, 0.f, 0.f);
    }
#pragma unroll
    for (int t = 0; t < TS_; ++t) {
      float a0 = bb.x, a1 = bb.y, a2 = bb.z, a3 = bb.w;
#pragma unroll
      for (int k = 0; k < 4; ++k) {
        float4 xv = xr[t + k];
        a0 += xv.x * wf[0][k];
        a1 += xv.y * wf[1][k];
        a2 += xv.z * wf[2][k];
        a3 += xv.w * wf[3][k];
      }
      bh4 ov;
      ov.h[0] = f2b(a0); ov.h[1] = f2b(a1); ov.h[2] = f2b(a2); ov.h[3] = f2b(a3);
      *(bh4*)(dw_out + (size_t)(m0 + t) * D_ + d) = ov;
    }
  } else {
    size_t i = ((size_t)(blockIdx.x - DWB) * 256 + threadIdx.x) * 4;
    const float* s; size_t off;
    if (i < 4194304) {
      if (i < 1048576)      { s = s0; off = 0; }
      else if (i < 2621440) { s = s1; off = 1048576; }
      else                  { s = s2; off = 2621440; }
    } else if (i < 7340032) {
      if (i < 5767168)      { s = s3; off = 4194304; }
      else                  { s = s4; off = 5767168; }
    } else {
      if (i < 11534336)     { s = s5; off = 7340032; }
      else                  { s = s6; off = 11534336; }
    }
    float4 v = *(const float4*)(s + (i - off));
    bh4 o;
    o.h[0] = f2b(v.x); o.h[1] = f2b(v.y); o.h[2] = f2b(v.z); o.h[3] = f2b(v.w);
    *(bh4*)(wdst + i) = o;
  }
}

// ---------------- shared epilogue ----------------
template<int EPI>
__device__ __forceinline__ void epi_store(float v, int row, int col, int N,
                                          const float* __restrict__ bias,
                                          const float* __restrict__ resid,
                                          bf16* outH, bf16* outH2, float* outF)
{
  size_t idx = (size_t)row * N + col;
  if constexpr (EPI == 0) {
    outH[idx] = f2b(v + bias[col] + resid[idx]);
  } else if constexpr (EPI == 1) {
    if (col < 1536) outH [(size_t)row * 1536 + col]        = f2b(v);
    else            outH2[(size_t)row * 1536 + col - 1536] = f2b(v);
  } else if constexpr (EPI == 2) {
    float gh = (v >= 0.f) ? (v + 0.5f) : (1.f / (1.f + expf(-v)));
    float iv = 1.f / (1.f + expf(-b2f(outH[idx])));
    outH[idx] = f2b(gh * iv);
  } else if constexpr (EPI == 3) {
    outH[idx] = f2b(v + resid[idx]);
  } else if constexpr (EPI == 4) {
    float u = v + bias[col];
    outH[idx] = f2b(0.5f * u * (1.f + erff(u * 0.70710678118f)));
  } else {
    outF[idx] = v + bias[col];
  }
}

// ======== GEMM 128x128 (proven): C(M,N)=A(M,K,lda)*B^T(N,K,ldb), bf16, swizzled LDS ========
// Sync structure frozen (stage-all -> sync -> 32 MFMA 16x16x32 -> sync). Pointer-bump
// staging; no XCD swizzle (R5/R7/R8 A/B: time-neutral, lower FETCH without); 16x16
// fragments (R6: 32x32 read pattern -> 8.4M bank conflicts). Row r chunk slot s holds
// col-group s^(r&7): measured 0-conflict.
template<int EPI>
__global__ __launch_bounds__(256) void gemm_ab(const bf16* __restrict__ A, int lda,
                                               const bf16* __restrict__ Bb, int ldb,
                                               const float* __restrict__ bias,
                                               const float* __restrict__ resid,
                                               bf16* outH, bf16* outH2, float* outF,
                                               int M, int N, int K)
{
  __shared__ __align__(16) bf16 lsA[128 * 64];
  __shared__ __align__(16) bf16 lsB[128 * 64];
  const int tid  = threadIdx.x;
  const int lane = tid & 63;
  const int wave = tid >> 6;
  const int m0 = blockIdx.y * 128, n0 = blockIdx.x * 128;
  const int wm = (wave >> 1) * 64, wn = (wave & 1) * 64;
  const int r = lane & 15, q = lane >> 4;
  const int sw = r & 7;
  f32x4 acc[4][4] = {};

  const bf16* pa[4]; const bf16* pb[4]; int dst[4];
#pragma unroll
  for (int i = 0; i < 4; ++i) {
    int c = i * 256 + tid;                     // LDS chunk id 0..1023
    int row = c >> 3, cc = (c & 7) ^ (row & 7);
    pa[i] = A  + (size_t)(m0 + row) * lda + cc * 8;
    pb[i] = Bb + (size_t)(n0 + row) * ldb + cc * 8;
    dst[i] = c * 16;
  }

  for (int k0 = 0; k0 < K; k0 += 64) {
#pragma unroll
    for (int i = 0; i < 4; ++i) {
      gld16(pa[i], (char*)lsA + dst[i]);
      gld16(pb[i], (char*)lsB + dst[i]);
      pa[i] += 64; pb[i] += 64;
    }
    __syncthreads();
#pragma unroll
    for (int kk = 0; kk < 64; kk += 32) {
      const int j = (kk >> 3) + q;
      s8v af[4], bfr[4];
#pragma unroll
      for (int t = 0; t < 4; ++t) {
        af[t]  = *(const s8v*)((char*)lsA + (((wm + t * 16 + r) << 3) + (j ^ sw)) * 16);
        bfr[t] = *(const s8v*)((char*)lsB + (((wn + t * 16 + r) << 3) + (j ^ sw)) * 16);
      }
#pragma unroll
      for (int mi = 0; mi < 4; ++mi)
#pragma unroll
        for (int ni = 0; ni < 4; ++ni)
          acc[mi][ni] = __builtin_amdgcn_mfma_f32_16x16x32_bf16(af[mi], bfr[ni], acc[mi][ni], 0, 0, 0);
    }
    __syncthreads();
  }

#pragma unroll
  for (int mi = 0; mi < 4; ++mi)
#pragma unroll
    for (int j = 0; j < 4; ++j) {
      int row = m0 + wm + mi * 16 + q * 4 + j;
#pragma unroll
      for (int ni = 0; ni < 4; ++ni)
        epi_store<EPI>(acc[mi][ni][j], row, n0 + wn + ni * 16 + r, N, bias, resid, outH, outH2, outF);
    }
}

// ---------------- LayerNorm over D=1024, bf16 in -> bf16 out (proven R5 block-per-row) ----------------
__global__ __launch_bounds__(256) void ln_k(const bf16* __restrict__ y,
                                            const float* __restrict__ g,
                                            const float* __restrict__ b,
                                            bf16* __restrict__ out)
{
  __shared__ float sm[8];
  int row = blockIdx.x;
  bh4 v4 = ((const bh4*)(y + (size_t)row * D_))[threadIdx.x];
  float v0 = b2f(v4.h[0]), v1 = b2f(v4.h[1]), v2 = b2f(v4.h[2]), v3 = b2f(v4.h[3]);
  float s = v0 + v1 + v2 + v3;
#pragma unroll
  for (int o = 32; o; o >>= 1) s += __shfl_down(s, o);
  int lane = threadIdx.x & 63, w = threadIdx.x >> 6;
  if (lane == 0) sm[w] = s;
  __syncthreads();
  float mu = (sm[0] + sm[1] + sm[2] + sm[3]) * (1.f / D_);
  float d0 = v0 - mu, d1 = v1 - mu, d2 = v2 - mu, d3 = v3 - mu;
  float qq = d0 * d0 + d1 * d1 + d2 * d2 + d3 * d3;
#pragma unroll
  for (int o = 32; o; o >>= 1) qq += __shfl_down(qq, o);
  if (lane == 0) sm[4 + w] = qq;
  __syncthreads();
  float var = (sm[4] + sm[5] + sm[6] + sm[7]) * (1.f / D_);
  float inv = rsqrtf(var + 1e-5f);
  int c = threadIdx.x * 4;
  float4 gv = *(const float4*)(g + c);
  float4 bv = *(const float4*)(b + c);
  bh4 ov;
  ov.h[0] = f2b(d0 * inv * gv.x + bv.x);
  ov.h[1] = f2b(d1 * inv * gv.y + bv.y);
  ov.h[2] = f2b(d2 * inv * gv.z + bv.z);
  ov.h[3] = f2b(d3 * inv * gv.w + bv.w);
  *(bh4*)(out + (size_t)row * D_ + c) = ov;
}

// ---------------- chunked linear-recurrence scan, vec8 (proven R5): h' = sigmoid(fpre)*h + g ----------------
__global__ __launch_bounds__(256) void scanA2_k(const bf16* __restrict__ fpre,
                                                const bf16* __restrict__ g,
                                                float* __restrict__ Fc, float* __restrict__ Gc)
{
  int t = blockIdx.x * 256 + threadIdx.x;       // 0 .. NCH*BE_/8-1
  int c = t / (BE_ / 8);
  int col = t % (BE_ / 8);
  int be8 = col * 8;
  int b = be8 / E_, e = be8 % E_;
  size_t idx = (size_t)b * S_ * E_ + (size_t)c * CHS * E_ + e;
  float F[8], G[8];
#pragma unroll
  for (int j = 0; j < 8; ++j) { F[j] = 1.f; G[j] = 0.f; }
  for (int sl = 0; sl < CHS; ++sl, idx += E_) {
    s8v fv8 = *(const s8v*)(fpre + idx);
    s8v gv8 = *(const s8v*)(g + idx);
#pragma unroll
    for (int j = 0; j < 8; ++j) {
      float fv = 1.f / (1.f + expf(-su2f(fv8[j])));
      F[j] *= fv;
      G[j] = fv * G[j] + su2f(gv8[j]);
    }
  }
  size_t o = (size_t)c * BE_ + be8;
  *(float4*)(Fc + o)     = make_float4(F[0], F[1], F[2], F[3]);
  *(float4*)(Fc + o + 4) = make_float4(F[4], F[5], F[6], F[7]);
  *(float4*)(Gc + o)     = make_float4(G[0], G[1], G[2], G[3]);
  *(float4*)(Gc + o + 4) = make_float4(G[4], G[5], G[6], G[7]);
}

__global__ __launch_bounds__(256) void scanB_k(const float* __restrict__ Fc,
                                               const float* __restrict__ Gc,
                                               float* __restrict__ hst)
{
  int be = blockIdx.x * 256 + threadIdx.x;
  float h = 0.5f;
#pragma unroll 16
  for (int c = 0; c < NCH; ++c) {
    hst[c * BE_ + be] = h;
    h = Fc[c * BE_ + be] * h + Gc[c * BE_ + be];
  }
}

__global__ __launch_bounds__(256) void scanC2_k(const bf16* __restrict__ fpre,
                                                bf16* g,
                                                const float* __restrict__ hst)
{
  int t = blockIdx.x * 256 + threadIdx.x;
  int c = t / (BE_ / 8);
  int col = t % (BE_ / 8);
  int be8 = col * 8;
  int b = be8 / E_, e = be8 % E_;
  size_t idx = (size_t)b * S_ * E_ + (size_t)c * CHS * E_ + e;
  size_t o = (size_t)c * BE_ + be8;
  float4 h0 = *(const float4*)(hst + o);
  float4 h1 = *(const float4*)(hst + o + 4);
  float h[8] = {h0.x, h0.y, h0.z, h0.w, h1.x, h1.y, h1.z, h1.w};
  for (int sl = 0; sl < CHS; ++sl, idx += E_) {
    s8v fv8 = *(const s8v*)(fpre + idx);
    s8v gv8 = *(const s8v*)(g + idx);
    bh8 ov;
#pragma unroll
    for (int j = 0; j < 8; ++j) {
      float fv = 1.f / (1.f + expf(-su2f(fv8[j])));
      h[j] = fv * h[j] + su2f(gv8[j]);
      ov.h[j] = f2b(h[j]);
    }
    *(bh8*)(g + idx) = ov;
  }
}

extern "C" void kernel_launch(void* const* d_in, const int* in_sizes, int n_in,
                              void* d_out, int out_size, void* d_ws, size_t ws_size,
                              hipStream_t stream)
{
  (void)in_sizes; (void)n_in; (void)out_size; (void)ws_size;
  const float* x      = (const float*)d_in[0];
  const float* cdw_w  = (const float*)d_in[1];
  const float* cdw_b  = (const float*)d_in[2];
  const float* cpw_w  = (const float*)d_in[3];
  const float* cpw_b  = (const float*)d_in[4];
  const float* ln1_g  = (const float*)d_in[5];
  const float* ln1_b  = (const float*)d_in[6];
  const float* w_f    = (const float*)d_in[7];
  const float* w_i    = (const float*)d_in[8];
  const float* w_h    = (const float*)d_in[9];
  const float* w_down = (const float*)d_in[10];
  const float* ln2_g  = (const float*)d_in[11];
  const float* ln2_b  = (const float*)d_in[12];
  const float* mlp_w1 = (const float*)d_in[13];
  const float* mlp_b1 = (const float*)d_in[14];
  const float* mlp_w2 = (const float*)d_in[15];
  const float* mlp_b2 = (const float*)d_in[16];
  char* ws = (char*)d_ws;
  float* outF = (float*)d_out;

  // [0,16M)   dw_buf(conv) / xln(ln outputs); Fc/Gc/hst @[0,9.4M) during scans (xln dead)
  // [16,32M)  yb ; [16,80M) hmid (over yb/fpre/gvals, dead by then)
  // [32,58M)  fpre raw bf16 ; [58,80M) ipre raw -> g (RMW by g2) -> h in-place (scanC2)
  // [80,110M) bf16 weights: pw | wfi | wh | wd | w1 | w2
  bf16* dw_buf = (bf16*)(ws + 0);
  bf16* xln    = (bf16*)(ws + 0);
  float* Fc    = (float*)(ws + 0);          // 128*6144*4 = 3,145,728
  float* Gc    = (float*)(ws + 3145728);
  float* hst   = (float*)(ws + 6291456);    // ends 9,437,184 < 16M
  bf16* yb     = (bf16*)(ws + 16777216);
  bf16* hmid   = (bf16*)(ws + 16777216);
  bf16* fpre   = (bf16*)(ws + 33554432);
  bf16* gvals  = (bf16*)(ws + 58720256);
  bf16* pwb    = (bf16*)(ws + 83886080);
  bf16* wfib   = (bf16*)(ws + 85983232);
  bf16* whb    = (bf16*)(ws + 92274688);
  bf16* wdb    = (bf16*)(ws + 95420416);
  bf16* w1b    = (bf16*)(ws + 98566144);
  bf16* w2b    = (bf16*)(ws + 106954752);

  // fused: dwconv (512 blocks) + weight cvt (15360 blocks)
  prep_k<<<DWB + 15360, 256, 0, stream>>>(x, cdw_w, cdw_b, dw_buf,
                                          cpw_w, w_f, w_i, w_h, w_down, mlp_w1, mlp_w2, pwb);

  gemm_ab<0><<<dim3(8, 64), 256, 0, stream>>>(dw_buf, D_, pwb, D_, cpw_b, x, yb, nullptr, nullptr, M_, D_, D_);
  ln_k<<<M_, 256, 0, stream>>>(yb, ln1_g, ln1_b, xln);
  // fused f+i raw pre-activations (N=3072), then h RMW: g = gh(v)*sigmoid(ipre)
  gemm_ab<1><<<dim3(24, 64), 256, 0, stream>>>(xln, D_, wfib, D_, nullptr, nullptr, fpre, gvals, nullptr, M_, 3072, D_);
  gemm_ab<2><<<dim3(12, 64), 256, 0, stream>>>(xln, D_, whb, D_, nullptr, nullptr, gvals, nullptr, nullptr, M_, E_, D_);
  scanA2_k<<<(NCH*BE_/8)/256, 256, 0, stream>>>(fpre, gvals, Fc, Gc);
  scanB_k<<<BE_/256, 256, 0, stream>>>(Fc, Gc, hst);
  scanC2_k<<<(NCH*BE_/8)/256, 256, 0, stream>>>(fpre, gvals, hst);
  gemm_ab<3><<<dim3(8, 64), 256, 0, stream>>>(gvals, E_, wdb, E_, nullptr, x, yb, nullptr, nullptr, M_, D_, E_);
  ln_k<<<M_, 256, 0, stream>>>(yb, ln2_g, ln2_b, xln);
  // fused MLP: one N=4096 GEMM -> hmid, one K=4096 GEMM -> d_out (fp32, single write)
  gemm_ab<4><<<dim3(32, 64), 256, 0, stream>>>(xln, D_, w1b, D_, mlp_b1, nullptr, hmid, nullptr, nullptr, M_, 4*D_, D_);
  gemm_ab<5><<<dim3(8, 64), 256, 0, stream>>>(hmid, 4*D_, w2b, 4*D_, mlp_b2, nullptr, nullptr, nullptr, outF, M_, D_, 4*D_);
}